// Round 8
// baseline (170.362 us; speedup 1.0000x reference)
//
#include <hip/hip_runtime.h>

#define NB    256
#define UNITS 1024
#define EDIM  1024
#define MEM   128
#define LDA   2048   // inputs row stride (EDIM + UNITS)

// d_out layout (floats): output[256*1024] | new_M_key[256*128*1024] | new_M_value[256*128*1024]
#define KEY_OFF ((size_t)NB * UNITS)
#define VAL_OFF (KEY_OFF + (size_t)NB * MEM * UNITS)

#define NGEMM 128                 // GEMM blocks (first in grid)
#define GROUP_F 4224              // GEMM: floats per split-K group region (As 32x68 + Bs 32x64)
#define SMEM_FLOATS (4 * GROUP_F) // 67584 B; fused path uses first ~21.5 KB

typedef float efloat4 __attribute__((ext_vector_type(4)));

// Force all 8 float4s live at one program point -> compiler must issue all 8
// global loads before the first consumer (memory-level parallelism pin).
#define PIN8(p0,p1,p2,p3,p4,p5,p6,p7)                                   \
    asm volatile("" :: "v"(*(const efloat4*)&(p0)), "v"(*(const efloat4*)&(p1)), \
                       "v"(*(const efloat4*)&(p2)), "v"(*(const efloat4*)&(p3)), \
                       "v"(*(const efloat4*)&(p4)), "v"(*(const efloat4*)&(p5)), \
                       "v"(*(const efloat4*)&(p6)), "v"(*(const efloat4*)&(p7)))

// Blocks 0..127: two 256x1024x1024 fp32 GEMMs (row 127 of new_M_*), LDS-staged,
//   in-block split-K=4 (R4 structure, proven).
// Blocks 128..383: fused path, R4 phase structure; streaming loops issue 8
//   float4 loads per batch, pinned live via PIN8 so the scheduler cannot
//   re-serialize them (R5-R7 lesson: source order alone leaves VGPR=32).
__global__ __launch_bounds__(1024, 8) void k_all(
    const float* __restrict__ inputs, const float* __restrict__ M_key,
    const float* __restrict__ M_value, const float* __restrict__ W_key,
    const float* __restrict__ W_value, float* __restrict__ out)
{
    __shared__ __align__(16) float smem[SMEM_FLOATS];
    const int tid = threadIdx.x;

    if (blockIdx.x >= NGEMM) {
        // ========================= fused path =========================
        float* h_s  = smem;                          // 1024
        float* lg_s = smem + 1024;                   // 128
        float* at_s = smem + 1152;                   // 128
        float (*red_s)[1024] = (float (*)[1024])(smem + 1280); // 4 x 1024

        const int b    = blockIdx.x - NGEMM;
        const int wave = tid >> 6;
        const int lane = tid & 63;

        h_s[tid] = inputs[(size_t)b * LDA + EDIM + tid];
        __syncthreads();                                       // bar 1

        const size_t mb = (size_t)b * (MEM * UNITS);
        const float* kb = M_key   + mb + lane * 4;
        float*       ko = out + KEY_OFF + mb + lane * 4;

        // ---- Phase A: K-pass, 2 rows per batch, 8 pinned loads ----
        float accr[8];
        #pragma unroll
        for (int rp = 0; rp < 8; rp += 2) {
            const int m0 = wave * 8 + rp;
            const int m1 = m0 + 1;
            const float* kr0 = kb + (size_t)m0 * UNITS;
            const float* kr1 = kb + (size_t)m1 * UNITS;

            float4 a0 = *(const float4*)(kr0);
            float4 a1 = *(const float4*)(kr0 + 256);
            float4 a2 = *(const float4*)(kr0 + 512);
            float4 a3 = *(const float4*)(kr0 + 768);
            float4 c0 = *(const float4*)(kr1);
            float4 c1 = *(const float4*)(kr1 + 256);
            float4 c2 = *(const float4*)(kr1 + 512);
            float4 c3 = *(const float4*)(kr1 + 768);
            PIN8(a0, a1, a2, a3, c0, c1, c2, c3);

            // h operands from LDS (keeps VGPR budget for the pinned loads)
            const float4 h0 = *(const float4*)(&h_s[lane * 4]);
            const float4 h1 = *(const float4*)(&h_s[lane * 4 + 256]);
            const float4 h2 = *(const float4*)(&h_s[lane * 4 + 512]);
            const float4 h3 = *(const float4*)(&h_s[lane * 4 + 768]);

            accr[rp] = a0.x*h0.x + a0.y*h0.y + a0.z*h0.z + a0.w*h0.w
                     + a1.x*h1.x + a1.y*h1.y + a1.z*h1.z + a1.w*h1.w
                     + a2.x*h2.x + a2.y*h2.y + a2.z*h2.z + a2.w*h2.w
                     + a3.x*h3.x + a3.y*h3.y + a3.z*h3.z + a3.w*h3.w;
            accr[rp + 1] = c0.x*h0.x + c0.y*h0.y + c0.z*h0.z + c0.w*h0.w
                         + c1.x*h1.x + c1.y*h1.y + c1.z*h1.z + c1.w*h1.w
                         + c2.x*h2.x + c2.y*h2.y + c2.z*h2.z + c2.w*h2.w
                         + c3.x*h3.x + c3.y*h3.y + c3.z*h3.z + c3.w*h3.w;

            if (m0 > 0) {
                float* kd0 = ko + (size_t)(m0 - 1) * UNITS;
                *(float4*)(kd0)       = a0;
                *(float4*)(kd0 + 256) = a1;
                *(float4*)(kd0 + 512) = a2;
                *(float4*)(kd0 + 768) = a3;
            }
            float* kd1 = ko + (size_t)(m1 - 1) * UNITS;
            *(float4*)(kd1)       = c0;
            *(float4*)(kd1 + 256) = c1;
            *(float4*)(kd1 + 512) = c2;
            *(float4*)(kd1 + 768) = c3;
        }

        // cross-lane reduces, off the stream path
        #pragma unroll
        for (int r = 0; r < 8; ++r) {
            float a = accr[r];
            #pragma unroll
            for (int off = 32; off > 0; off >>= 1)
                a += __shfl_xor(a, off);
            if (lane == 0) lg_s[wave * 8 + r] = a;
        }
        __syncthreads();                                       // bar 2

        // ---- softmax over 128 logits (wave 0) ----
        if (wave == 0) {
            float l0 = lg_s[lane], l1 = lg_s[lane + 64];
            float mx = fmaxf(l0, l1);
            #pragma unroll
            for (int off = 32; off > 0; off >>= 1)
                mx = fmaxf(mx, __shfl_xor(mx, off));
            float e0 = __expf(l0 - mx), e1 = __expf(l1 - mx);
            float s = e0 + e1;
            #pragma unroll
            for (int off = 32; off > 0; off >>= 1)
                s += __shfl_xor(s, off);
            float inv = 1.0f / s;
            at_s[lane]      = e0 * inv;
            at_s[lane + 64] = e1 * inv;
        }
        __syncthreads();                                       // bar 3

        // ---- Phase C: V-pass, 8 rows per batch, 8 pinned loads ----
        {
            const int rc  = wave >> 2;                 // 0..3 -> 32 rows each
            const int col = (wave & 3) * 256 + lane * 4;
            const float* vbase = M_value + mb + col;
            float*       dbase = out + VAL_OFF + mb + col;

            float4 acc = {0.f, 0.f, 0.f, 0.f};
            #pragma unroll
            for (int r = 0; r < 32; r += 8) {
                const int m = rc * 32 + r;
                float4 v0 = *(const float4*)(vbase + (size_t)(m + 0) * UNITS);
                float4 v1 = *(const float4*)(vbase + (size_t)(m + 1) * UNITS);
                float4 v2 = *(const float4*)(vbase + (size_t)(m + 2) * UNITS);
                float4 v3 = *(const float4*)(vbase + (size_t)(m + 3) * UNITS);
                float4 v4 = *(const float4*)(vbase + (size_t)(m + 4) * UNITS);
                float4 v5 = *(const float4*)(vbase + (size_t)(m + 5) * UNITS);
                float4 v6 = *(const float4*)(vbase + (size_t)(m + 6) * UNITS);
                float4 v7 = *(const float4*)(vbase + (size_t)(m + 7) * UNITS);
                PIN8(v0, v1, v2, v3, v4, v5, v6, v7);

                const float w0 = at_s[m + 0], w1 = at_s[m + 1];
                const float w2 = at_s[m + 2], w3 = at_s[m + 3];
                const float w4 = at_s[m + 4], w5 = at_s[m + 5];
                const float w6 = at_s[m + 6], w7 = at_s[m + 7];

                acc.x = fmaf(w0, v0.x, acc.x); acc.y = fmaf(w0, v0.y, acc.y);
                acc.z = fmaf(w0, v0.z, acc.z); acc.w = fmaf(w0, v0.w, acc.w);
                acc.x = fmaf(w1, v1.x, acc.x); acc.y = fmaf(w1, v1.y, acc.y);
                acc.z = fmaf(w1, v1.z, acc.z); acc.w = fmaf(w1, v1.w, acc.w);
                acc.x = fmaf(w2, v2.x, acc.x); acc.y = fmaf(w2, v2.y, acc.y);
                acc.z = fmaf(w2, v2.z, acc.z); acc.w = fmaf(w2, v2.w, acc.w);
                acc.x = fmaf(w3, v3.x, acc.x); acc.y = fmaf(w3, v3.y, acc.y);
                acc.z = fmaf(w3, v3.z, acc.z); acc.w = fmaf(w3, v3.w, acc.w);
                acc.x = fmaf(w4, v4.x, acc.x); acc.y = fmaf(w4, v4.y, acc.y);
                acc.z = fmaf(w4, v4.z, acc.z); acc.w = fmaf(w4, v4.w, acc.w);
                acc.x = fmaf(w5, v5.x, acc.x); acc.y = fmaf(w5, v5.y, acc.y);
                acc.z = fmaf(w5, v5.z, acc.z); acc.w = fmaf(w5, v5.w, acc.w);
                acc.x = fmaf(w6, v6.x, acc.x); acc.y = fmaf(w6, v6.y, acc.y);
                acc.z = fmaf(w6, v6.z, acc.z); acc.w = fmaf(w6, v6.w, acc.w);
                acc.x = fmaf(w7, v7.x, acc.x); acc.y = fmaf(w7, v7.y, acc.y);
                acc.z = fmaf(w7, v7.z, acc.z); acc.w = fmaf(w7, v7.w, acc.w);

                if (m > 0)
                    *(float4*)(dbase + (size_t)(m - 1) * UNITS) = v0;
                *(float4*)(dbase + (size_t)(m + 0) * UNITS) = v1;
                *(float4*)(dbase + (size_t)(m + 1) * UNITS) = v2;
                *(float4*)(dbase + (size_t)(m + 2) * UNITS) = v3;
                *(float4*)(dbase + (size_t)(m + 3) * UNITS) = v4;
                *(float4*)(dbase + (size_t)(m + 4) * UNITS) = v5;
                *(float4*)(dbase + (size_t)(m + 5) * UNITS) = v6;
                *(float4*)(dbase + (size_t)(m + 6) * UNITS) = v7;
            }
            *(float4*)(&red_s[rc][col]) = acc;
        }
        __syncthreads();                                       // bar 4

        if (wave < 4) {
            const int col = wave * 256 + lane * 4;
            float4 a0 = *(const float4*)(&red_s[0][col]);
            float4 a1 = *(const float4*)(&red_s[1][col]);
            float4 a2 = *(const float4*)(&red_s[2][col]);
            float4 a3 = *(const float4*)(&red_s[3][col]);
            float4 s = {a0.x + a1.x + a2.x + a3.x,
                        a0.y + a1.y + a2.y + a3.y,
                        a0.z + a1.z + a2.z + a3.z,
                        a0.w + a1.w + a2.w + a3.w};
            *(float4*)(out + (size_t)b * UNITS + col) = s;
        }
    } else {
        // ========================= GEMM path (R4 structure) =========================
        const int t  = blockIdx.x;            // 0..127
        const int w  = t >> 6;                // which W matrix
        const int r  = t & 63;
        const int mt = r >> 4;                // 0..3  (64 rows)
        const int nt = r & 15;                // 0..15 (64 cols)
        const int kc   = tid >> 8;            // 0..3 (split-K group)
        const int gtid = tid & 255;
        const int ty = gtid >> 4, tx = gtid & 15;

        float* region = smem + kc * GROUP_F;
        float (*As)[68] = (float (*)[68])region;            // [k][m]
        float (*Bs)[64] = (float (*)[64])(region + 2176);   // [k][n]
        const float* Wm = w ? W_value : W_key;

        float acc[4][4] = {};
        const int k0 = kc * 256;

        for (int kt = k0; kt < k0 + 256; kt += 32) {
            #pragma unroll
            for (int q = 0; q < 2; ++q) {
                const int f  = gtid * 2 + q;          // 0..511
                const int ar = f >> 3;                // 0..63
                const int ac = (f & 7) << 2;          // 0..28
                float4 a = *(const float4*)(inputs + (size_t)(mt * 64 + ar) * LDA + kt + ac);
                As[ac + 0][ar] = a.x;
                As[ac + 1][ar] = a.y;
                As[ac + 2][ar] = a.z;
                As[ac + 3][ar] = a.w;
            }
            #pragma unroll
            for (int q = 0; q < 2; ++q) {
                const int f  = gtid * 2 + q;
                const int br = f >> 4;                // 0..31
                const int bc = (f & 15) << 2;         // 0..60
                *(float4*)(&Bs[br][bc]) =
                    *(const float4*)(Wm + (size_t)(kt + br) * UNITS + nt * 64 + bc);
            }
            __syncthreads();

            #pragma unroll
            for (int kk = 0; kk < 32; ++kk) {
                const float4 av = *(const float4*)(&As[kk][ty * 4]);
                const float4 bv = *(const float4*)(&Bs[kk][tx * 4]);
                acc[0][0] += av.x * bv.x; acc[0][1] += av.x * bv.y; acc[0][2] += av.x * bv.z; acc[0][3] += av.x * bv.w;
                acc[1][0] += av.y * bv.x; acc[1][1] += av.y * bv.y; acc[1][2] += av.y * bv.z; acc[1][3] += av.y * bv.w;
                acc[2][0] += av.z * bv.x; acc[2][1] += av.z * bv.y; acc[2][2] += av.z * bv.z; acc[2][3] += av.z * bv.w;
                acc[3][0] += av.w * bv.x; acc[3][1] += av.w * bv.y; acc[3][2] += av.w * bv.z; acc[3][3] += av.w * bv.w;
            }
            __syncthreads();
        }

        // each group writes its 64x64 partial over its own As/Bs region
        #pragma unroll
        for (int i = 0; i < 4; ++i) {
            float4 v = {acc[i][0], acc[i][1], acc[i][2], acc[i][3]};
            *(float4*)(region + (ty * 4 + i) * 64 + tx * 4) = v;
        }
        __syncthreads();

        // block-wide reduce of the 4 partials -> row 127 of new_M_{key,value}
        {
            const int e   = tid * 4;                  // 0..4092
            const int row = e >> 6;                   // 0..63
            const int col = e & 63;
            float4 p0 = *(const float4*)(smem + 0 * GROUP_F + e);
            float4 p1 = *(const float4*)(smem + 1 * GROUP_F + e);
            float4 p2 = *(const float4*)(smem + 2 * GROUP_F + e);
            float4 p3 = *(const float4*)(smem + 3 * GROUP_F + e);
            float4 s = {p0.x + p1.x + p2.x + p3.x,
                        p0.y + p1.y + p2.y + p3.y,
                        p0.z + p1.z + p2.z + p3.z,
                        p0.w + p1.w + p2.w + p3.w};
            *(float4*)(out + (w ? VAL_OFF : KEY_OFF)
                       + (size_t)(mt * 64 + row) * (MEM * UNITS)
                       + (size_t)(MEM - 1) * UNITS + nt * 64 + col) = s;
        }
    }
}

extern "C" void kernel_launch(void* const* d_in, const int* in_sizes, int n_in,
                              void* d_out, int out_size, void* d_ws, size_t ws_size,
                              hipStream_t stream)
{
    const float* inputs  = (const float*)d_in[0];
    const float* M_key   = (const float*)d_in[1];
    const float* M_value = (const float*)d_in[2];
    const float* W_key   = (const float*)d_in[3];
    const float* W_value = (const float*)d_in[4];
    float* out = (float*)d_out;

    hipLaunchKernelGGL(k_all, dim3(NGEMM + NB), dim3(1024), 0, stream,
                       inputs, M_key, M_value, W_key, W_value, out);
}

// Round 9
// 111.147 us; speedup vs baseline: 1.5328x; 1.5328x over previous
//
#include <hip/hip_runtime.h>

#define NB    256
#define UNITS 1024
#define EDIM  1024
#define MEM   128
#define LDA   2048   // inputs row stride (EDIM + UNITS)

// d_out layout (floats): output[256*1024] | new_M_key[256*128*1024] | new_M_value[256*128*1024]
#define KEY_OFF ((size_t)NB * UNITS)
#define VAL_OFF (KEY_OFF + (size_t)NB * MEM * UNITS)

#define NGEMM 128                 // GEMM blocks (last in grid, R4 order)
#define GROUP_F 4224              // GEMM: floats per split-K group region (As 32x68 + Bs 32x64)

// fused-path LDS: buf[2][8192] (2x32KB tiles) | h 1024 | lg2 256 | at 128
#define BUF0    0
#define H_OFF   16384
#define LG2_OFF 17408
#define AT_OFF  17664
#define SMEM_FLOATS 17792         // 71168 B (>= GEMM's 4*GROUP_F = 16896)

// async global->LDS DMA: 16B per lane, wave-uniform LDS base + lane*16
__device__ __forceinline__ void dma16(const float* g, float* l) {
    __builtin_amdgcn_global_load_lds((const __attribute__((address_space(1))) void*)g,
                                     (__attribute__((address_space(3))) void*)l, 16, 0, 0);
}

// Blocks 0..255: fused attention + shift. Streams M_key then M_value in 32KB
//   tiles via global_load_lds (deep fire-and-forget read bursts, no VGPR cost),
//   one __syncthreads per tile; consume = LDS reads + dot/fma + contiguous
//   copy stores. Per tile, wave w stages chunks (2KB) and consumes row (w&7),
//   half (w>>3).
// Blocks 256..383: two 256x1024x1024 fp32 GEMMs (row 127 of new_M_*),
//   LDS-staged, in-block split-K=4 (R4 structure, proven).
__global__ __launch_bounds__(1024, 8) void k_all(
    const float* __restrict__ inputs, const float* __restrict__ M_key,
    const float* __restrict__ M_value, const float* __restrict__ W_key,
    const float* __restrict__ W_value, float* __restrict__ out)
{
    __shared__ __align__(16) float smem[SMEM_FLOATS];
    const int tid = threadIdx.x;

    if (blockIdx.x < NB) {
        // ========================= fused path =========================
        const int b    = blockIdx.x;
        const int wave = tid >> 6;
        const int lane = tid & 63;
        const int r    = wave & 7;     // row within tile this wave consumes
        const int hh   = wave >> 3;    // column half (0: cols 0-511, 1: 512-1023)

        const size_t mb = (size_t)b * (MEM * UNITS);
        const float* kbase = M_key   + mb;
        const float* vbase = M_value + mb;
        float*       kout  = out + KEY_OFF + mb;
        float*       vout  = out + VAL_OFF + mb;

        smem[H_OFF + tid] = inputs[(size_t)b * LDA + EDIM + tid];

        // prologue: stage K tile 0 into buf0
        {
            const float* src = kbase;
            #pragma unroll
            for (int c = 0; c < 2; ++c) {
                const int off = (wave * 2 + c) * 256;
                dma16(src + off + lane * 4, smem + BUF0 + off);
            }
        }
        __syncthreads();   // h ready + tile 0 landed

        const float4 h0 = *(const float4*)(&smem[H_OFF + hh * 512 + lane * 4]);
        const float4 h1 = *(const float4*)(&smem[H_OFF + hh * 512 + lane * 4 + 256]);

        // ---- Phase A: K-pass, 16 tiles of 8 rows ----
        for (int t = 0; t < 16; ++t) {
            if (t < 15) {   // issue next tile's DMA burst
                const float* src = kbase + (size_t)(t + 1) * 8192;
                float* lb = smem + ((t + 1) & 1) * 8192;
                #pragma unroll
                for (int c = 0; c < 2; ++c) {
                    const int off = (wave * 2 + c) * 256;
                    dma16(src + off + lane * 4, lb + off);
                }
            }
            // consume tile t
            {
                const float* lb = smem + (t & 1) * 8192;
                const int base = r * 1024 + hh * 512 + lane * 4;
                float4 x0 = *(const float4*)(lb + base);
                float4 x1 = *(const float4*)(lb + base + 256);

                float a = x0.x*h0.x + x0.y*h0.y + x0.z*h0.z + x0.w*h0.w
                        + x1.x*h1.x + x1.y*h1.y + x1.z*h1.z + x1.w*h1.w;
                #pragma unroll
                for (int off = 32; off > 0; off >>= 1)
                    a += __shfl_xor(a, off);
                const int m = t * 8 + r;
                if (lane == 0) smem[LG2_OFF + m * 2 + hh] = a;

                if (m > 0) {
                    float* dst = kout + (size_t)(m - 1) * 1024 + hh * 512 + lane * 4;
                    *(float4*)(dst)       = x0;
                    *(float4*)(dst + 256) = x1;
                }
            }
            __syncthreads();   // drains next-tile DMA; consume(t) complete
        }

        // ---- softmax over 128 logits (wave 0) + stage V tile 0 ----
        if (wave == 0) {
            float l0 = smem[LG2_OFF + lane * 2]       + smem[LG2_OFF + lane * 2 + 1];
            float l1 = smem[LG2_OFF + (lane + 64) * 2] + smem[LG2_OFF + (lane + 64) * 2 + 1];
            float mx = fmaxf(l0, l1);
            #pragma unroll
            for (int off = 32; off > 0; off >>= 1)
                mx = fmaxf(mx, __shfl_xor(mx, off));
            float e0 = __expf(l0 - mx), e1 = __expf(l1 - mx);
            float s = e0 + e1;
            #pragma unroll
            for (int off = 32; off > 0; off >>= 1)
                s += __shfl_xor(s, off);
            float inv = 1.0f / s;
            smem[AT_OFF + lane]      = e0 * inv;
            smem[AT_OFF + lane + 64] = e1 * inv;
        }
        {
            const float* src = vbase;
            #pragma unroll
            for (int c = 0; c < 2; ++c) {
                const int off = (wave * 2 + c) * 256;
                dma16(src + off + lane * 4, smem + BUF0 + off);
            }
        }
        __syncthreads();   // at_s ready + V tile 0 landed

        // ---- Phase C: V-pass, 16 tiles of 8 rows ----
        float4 acc0 = {0.f, 0.f, 0.f, 0.f};
        float4 acc1 = {0.f, 0.f, 0.f, 0.f};
        for (int t = 0; t < 16; ++t) {
            if (t < 15) {
                const float* src = vbase + (size_t)(t + 1) * 8192;
                float* lb = smem + ((t + 1) & 1) * 8192;
                #pragma unroll
                for (int c = 0; c < 2; ++c) {
                    const int off = (wave * 2 + c) * 256;
                    dma16(src + off + lane * 4, lb + off);
                }
            }
            {
                const float* lb = smem + (t & 1) * 8192;
                const int base = r * 1024 + hh * 512 + lane * 4;
                float4 x0 = *(const float4*)(lb + base);
                float4 x1 = *(const float4*)(lb + base + 256);

                const int m = t * 8 + r;
                const float w = smem[AT_OFF + m];
                acc0.x = fmaf(w, x0.x, acc0.x); acc0.y = fmaf(w, x0.y, acc0.y);
                acc0.z = fmaf(w, x0.z, acc0.z); acc0.w = fmaf(w, x0.w, acc0.w);
                acc1.x = fmaf(w, x1.x, acc1.x); acc1.y = fmaf(w, x1.y, acc1.y);
                acc1.z = fmaf(w, x1.z, acc1.z); acc1.w = fmaf(w, x1.w, acc1.w);

                if (m > 0) {
                    float* dst = vout + (size_t)(m - 1) * 1024 + hh * 512 + lane * 4;
                    *(float4*)(dst)       = x0;
                    *(float4*)(dst + 256) = x1;
                }
            }
            __syncthreads();
        }

        // per-wave output partials -> red (aliases buf0; tile14 region, dead)
        *(float4*)(&smem[wave * 512 + lane * 4])       = acc0;
        *(float4*)(&smem[wave * 512 + lane * 4 + 256]) = acc1;
        __syncthreads();

        // combine 8 wave-partials per column half; at_s already normalized
        {
            const int idx = tid & 511;
            const int hb  = (tid >> 9) * 8;   // waves 0-7 -> cols 0-511, 8-15 -> 512-1023
            float s = 0.f;
            #pragma unroll
            for (int w = 0; w < 8; ++w)
                s += smem[(hb + w) * 512 + idx];
            out[(size_t)b * UNITS + tid] = s;
        }
    } else {
        // ========================= GEMM path (R4 structure) =========================
        const int t  = blockIdx.x - NB;       // 0..127
        const int w  = t >> 6;                // which W matrix
        const int rr = t & 63;
        const int mt = rr >> 4;               // 0..3  (64 rows)
        const int nt = rr & 15;               // 0..15 (64 cols)
        const int kc   = tid >> 8;            // 0..3 (split-K group)
        const int gtid = tid & 255;
        const int ty = gtid >> 4, tx = gtid & 15;

        float* region = smem + kc * GROUP_F;
        float (*As)[68] = (float (*)[68])region;            // [k][m]
        float (*Bs)[64] = (float (*)[64])(region + 2176);   // [k][n]
        const float* Wm = w ? W_value : W_key;

        float acc[4][4] = {};
        const int k0 = kc * 256;

        for (int kt = k0; kt < k0 + 256; kt += 32) {
            #pragma unroll
            for (int q = 0; q < 2; ++q) {
                const int f  = gtid * 2 + q;          // 0..511
                const int ar = f >> 3;                // 0..63
                const int ac = (f & 7) << 2;          // 0..28
                float4 a = *(const float4*)(inputs + (size_t)(mt * 64 + ar) * LDA + kt + ac);
                As[ac + 0][ar] = a.x;
                As[ac + 1][ar] = a.y;
                As[ac + 2][ar] = a.z;
                As[ac + 3][ar] = a.w;
            }
            #pragma unroll
            for (int q = 0; q < 2; ++q) {
                const int f  = gtid * 2 + q;
                const int br = f >> 4;                // 0..31
                const int bc = (f & 15) << 2;         // 0..60
                *(float4*)(&Bs[br][bc]) =
                    *(const float4*)(Wm + (size_t)(kt + br) * UNITS + nt * 64 + bc);
            }
            __syncthreads();

            #pragma unroll
            for (int kk = 0; kk < 32; ++kk) {
                const float4 av = *(const float4*)(&As[kk][ty * 4]);
                const float4 bv = *(const float4*)(&Bs[kk][tx * 4]);
                acc[0][0] += av.x * bv.x; acc[0][1] += av.x * bv.y; acc[0][2] += av.x * bv.z; acc[0][3] += av.x * bv.w;
                acc[1][0] += av.y * bv.x; acc[1][1] += av.y * bv.y; acc[1][2] += av.y * bv.z; acc[1][3] += av.y * bv.w;
                acc[2][0] += av.z * bv.x; acc[2][1] += av.z * bv.y; acc[2][2] += av.z * bv.z; acc[2][3] += av.z * bv.w;
                acc[3][0] += av.w * bv.x; acc[3][1] += av.w * bv.y; acc[3][2] += av.w * bv.z; acc[3][3] += av.w * bv.w;
            }
            __syncthreads();
        }

        // each group writes its 64x64 partial over its own As/Bs region
        #pragma unroll
        for (int i = 0; i < 4; ++i) {
            float4 v = {acc[i][0], acc[i][1], acc[i][2], acc[i][3]};
            *(float4*)(region + (ty * 4 + i) * 64 + tx * 4) = v;
        }
        __syncthreads();

        // block-wide reduce of the 4 partials -> row 127 of new_M_{key,value}
        {
            const int e   = tid * 4;                  // 0..4092
            const int row = e >> 6;                   // 0..63
            const int col = e & 63;
            float4 p0 = *(const float4*)(smem + 0 * GROUP_F + e);
            float4 p1 = *(const float4*)(smem + 1 * GROUP_F + e);
            float4 p2 = *(const float4*)(smem + 2 * GROUP_F + e);
            float4 p3 = *(const float4*)(smem + 3 * GROUP_F + e);
            float4 s = {p0.x + p1.x + p2.x + p3.x,
                        p0.y + p1.y + p2.y + p3.y,
                        p0.z + p1.z + p2.z + p3.z,
                        p0.w + p1.w + p2.w + p3.w};
            *(float4*)(out + (w ? VAL_OFF : KEY_OFF)
                       + (size_t)(mt * 64 + row) * (MEM * UNITS)
                       + (size_t)(MEM - 1) * UNITS + nt * 64 + col) = s;
        }
    }
}

extern "C" void kernel_launch(void* const* d_in, const int* in_sizes, int n_in,
                              void* d_out, int out_size, void* d_ws, size_t ws_size,
                              hipStream_t stream)
{
    const float* inputs  = (const float*)d_in[0];
    const float* M_key   = (const float*)d_in[1];
    const float* M_value = (const float*)d_in[2];
    const float* W_key   = (const float*)d_in[3];
    const float* W_value = (const float*)d_in[4];
    float* out = (float*)d_out;

    hipLaunchKernelGGL(k_all, dim3(NB + NGEMM), dim3(1024), 0, stream,
                       inputs, M_key, M_value, W_key, W_value, out);
}